// Round 6
// baseline (943.885 us; speedup 1.0000x reference)
//
#include <hip/hip_runtime.h>
#include <hip/hip_bf16.h>
#include <hip/hip_cooperative_groups.h>

namespace cg = cooperative_groups;

#define RANK    200
#define N_ENT   200000
#define N_REL   500
#define NNZ     500000
#define NB_WIN  256         // fallback winner stage-1 blocks
#define NB_COOP 1024        // cooperative grid (4 blocks/CU, 16 waves/CU)
#define WB_PAD  512         // padded relation slots per partial row

// Native 4-float vector: __builtin_nontemporal_store requires a native
// vector type, not HIP's float4 class.
typedef float f32x4 __attribute__((ext_vector_type(4)));

__device__ __forceinline__ void nt_store4(float* p,
                                          float a, float b_, float c, float d) {
    f32x4 v = {a, b_, c, d};
    __builtin_nontemporal_store(v, (f32x4*)p);
}

// ---------------------------------------------------------------------------
// Winner semantics (numpy scatter-SET, last write wins):
//   grad_a[subj] = g_a (pass 1) then grad_a[obj] = g_c (pass 2 overwrites).
// wA key: subj write at nnz i -> i ; obj write -> NNZ+i. wB winner = max i
// per relation (LDS-aggregated; 500-address global atomics serialize).
// ---------------------------------------------------------------------------

// ======================= cooperative mega-kernel ===========================
// P0 init wA/lwB -> P1 winner scan -> P2 wB reduce -> P3 fused loss+grad
// -> P4 zero-fill untouched rows (disjoint from P3's rows: no sync needed).
// One dispatch: no inter-kernel gaps, no memset dispatch, winner phase runs
// at 16 waves/CU instead of 4.
__global__ void __launch_bounds__(256, 4) mega_kernel(
        const int* __restrict__ coo, const float* __restrict__ vals,
        const float* __restrict__ a, const float* __restrict__ b,
        float* __restrict__ loss, float* __restrict__ grad_a,
        float* __restrict__ grad_b, int* __restrict__ wA,
        int* __restrict__ wB, int* __restrict__ partial_wB) {
    cg::grid_group grid = cg::this_grid();
    __shared__ int lwB[WB_PAD];
    const int tid  = threadIdx.x;
    const int gtid = blockIdx.x * blockDim.x + tid;
    const int gsz  = gridDim.x * blockDim.x;          // 262144
    const int lane = tid & 63;

    // ---- P0: init ----
    for (int t = tid; t < WB_PAD; t += blockDim.x) lwB[t] = -1;
    for (int t = gtid; t < N_ENT; t += gsz) wA[t] = -1;
    __syncthreads();
    __threadfence();
    grid.sync();

    // ---- P1: winner scan ----
    for (int i = gtid; i < NNZ; i += gsz) {
        int s = coo[3 * i + 0];
        int r = coo[3 * i + 1];
        int o = coo[3 * i + 2];
        atomicMax(&wA[s], i);           // ~5 contenders per address
        atomicMax(&wA[o], NNZ + i);
        atomicMax(&lwB[r], i);          // LDS atomic, per-block
    }
    __syncthreads();
    for (int t = tid; t < WB_PAD; t += blockDim.x)
        partial_wB[(size_t)blockIdx.x * WB_PAD + t] = lwB[t];
    __threadfence();
    grid.sync();

    // ---- P2: wB reduce — wave w owns relation w ----
    int wid = gtid >> 6;
    if (wid < WB_PAD) {
        int m = -1;
        for (int k = lane; k < NB_COOP; k += 64)
            m = max(m, partial_wB[(size_t)k * WB_PAD + wid]);
        #pragma unroll
        for (int off = 32; off > 0; off >>= 1)
            m = max(m, __shfl_xor(m, off, 64));
        if (lane == 0) wB[wid] = m;
    }
    __threadfence();
    grid.sync();

    // ---- P3: fused loss+grad, one wave per nnz, grid-stride by wave ----
    const int nwaves = gsz >> 6;                      // 4096
    for (int i = (gtid >> 6); i < NNZ; i += nwaves) {
        int s = coo[3 * i + 0];
        int r = coo[3 * i + 1];
        int o = coo[3 * i + 2];
        int ks = wA[s];
        int ko = wA[o];
        int kr = wB[r];

        float4 x = make_float4(0.f, 0.f, 0.f, 0.f);
        float4 y = x, z = x;
        float sum = 0.0f;
        if (lane < RANK / 4) {
            x = ((const float4*)(a + (size_t)s * RANK))[lane];
            y = ((const float4*)(b + (size_t)r * RANK))[lane];
            z = ((const float4*)(a + (size_t)o * RANK))[lane];
            sum = x.x * y.x * z.x + x.y * y.y * z.y
                + x.z * y.z * z.z + x.w * y.w * z.w;
        }
        #pragma unroll
        for (int off = 32; off > 0; off >>= 1)
            sum += __shfl_xor(sum, off, 64);

        float d = sum - vals[i];
        if (lane == 0) __builtin_nontemporal_store(d * d, &loss[i]);
        float d2 = 2.0f * d;

        if (lane < RANK / 4) {
            if (ks == i) {                      // g_a = d2 * b1 * a2
                float* outp = grad_a + (size_t)s * RANK + lane * 4;
                nt_store4(outp, d2 * y.x * z.x, d2 * y.y * z.y,
                                d2 * y.z * z.z, d2 * y.w * z.w);
            }
            if (ko == NNZ + i) {                // g_c = d2 * a0 * b1
                float* outp = grad_a + (size_t)o * RANK + lane * 4;
                nt_store4(outp, d2 * x.x * y.x, d2 * x.y * y.y,
                                d2 * x.z * y.z, d2 * x.w * y.w);
            }
            if (kr == i) {                      // g_b = d2 * a0 * a2
                float* outp = grad_b + (size_t)r * RANK + lane * 4;
                nt_store4(outp, d2 * x.x * z.x, d2 * x.y * z.y,
                                d2 * x.z * z.z, d2 * x.w * z.w);
            }
        }
    }

    // ---- P4: zero untouched rows (disjoint from P3's winner rows) ----
    // gsz = 262144 >= N_ENT + N_REL, single shot.
    {
        bool need = false;
        if (gtid < N_ENT)                   need = (wA[gtid] < 0);
        else if (gtid < N_ENT + N_REL)      need = (wB[gtid - N_ENT] < 0);
        unsigned long long mask = __ballot(need);
        while (mask) {
            int src = __ffsll((long long)mask) - 1;
            mask &= mask - 1;
            int rowsel = __shfl(gtid, src, 64);
            float* outp = (rowsel < N_ENT)
                ? (grad_a + (size_t)rowsel * RANK)
                : (grad_b + (size_t)(rowsel - N_ENT) * RANK);
            if (lane < RANK / 4)
                nt_store4(outp + lane * 4, 0.f, 0.f, 0.f, 0.f);
        }
    }
}

// ========================= fallback path (round-5) =========================
__global__ void winner_kernel(const int* __restrict__ coo,
                              int* __restrict__ wA,
                              int* __restrict__ partial_wB) {
    __shared__ int lwB[WB_PAD];
    for (int t = threadIdx.x; t < WB_PAD; t += blockDim.x) lwB[t] = -1;
    __syncthreads();

    int gtid   = blockIdx.x * blockDim.x + threadIdx.x;
    int stride = gridDim.x * blockDim.x;
    for (int i = gtid; i < NNZ; i += stride) {
        int s = coo[3 * i + 0];
        int r = coo[3 * i + 1];
        int o = coo[3 * i + 2];
        atomicMax(&wA[s], i);
        atomicMax(&wA[o], NNZ + i);
        atomicMax(&lwB[r], i);
    }
    __syncthreads();
    int* out = partial_wB + (size_t)blockIdx.x * WB_PAD;
    for (int t = threadIdx.x; t < WB_PAD; t += blockDim.x) out[t] = lwB[t];
}

__global__ void wb_reduce_kernel(const int* __restrict__ partial_wB,
                                 int* __restrict__ wB) {
    int t = threadIdx.x;
    int m = -1;
    for (int nb = 0; nb < NB_WIN; ++nb)
        m = max(m, partial_wB[(size_t)nb * WB_PAD + t]);
    if (t < N_REL) wB[t] = m;
}

__global__ void fused_kernel(const int* __restrict__ coo,
                             const float* __restrict__ vals,
                             const float* __restrict__ a,
                             const float* __restrict__ b,
                             const int* __restrict__ wA,
                             const int* __restrict__ wB,
                             float* __restrict__ loss,
                             float* __restrict__ grad_a,
                             float* __restrict__ grad_b) {
    int wave = (blockIdx.x * blockDim.x + threadIdx.x) >> 6;
    int lane = threadIdx.x & 63;
    if (wave >= NNZ) return;
    int s = coo[3 * wave + 0];
    int r = coo[3 * wave + 1];
    int o = coo[3 * wave + 2];
    int ks = wA[s];
    int ko = wA[o];
    int kr = wB[r];

    float4 x = make_float4(0.f, 0.f, 0.f, 0.f);
    float4 y = x, z = x;
    float sum = 0.0f;
    if (lane < RANK / 4) {
        x = ((const float4*)(a + (size_t)s * RANK))[lane];
        y = ((const float4*)(b + (size_t)r * RANK))[lane];
        z = ((const float4*)(a + (size_t)o * RANK))[lane];
        sum = x.x * y.x * z.x + x.y * y.y * z.y
            + x.z * y.z * z.z + x.w * y.w * z.w;
    }
    #pragma unroll
    for (int off = 32; off > 0; off >>= 1)
        sum += __shfl_xor(sum, off, 64);

    float d = sum - vals[wave];
    if (lane == 0) __builtin_nontemporal_store(d * d, &loss[wave]);
    float d2 = 2.0f * d;

    if (lane < RANK / 4) {
        if (ks == wave) {
            float* outp = grad_a + (size_t)s * RANK + lane * 4;
            nt_store4(outp, d2 * y.x * z.x, d2 * y.y * z.y,
                            d2 * y.z * z.z, d2 * y.w * z.w);
        }
        if (ko == NNZ + wave) {
            float* outp = grad_a + (size_t)o * RANK + lane * 4;
            nt_store4(outp, d2 * x.x * y.x, d2 * x.y * y.y,
                            d2 * x.z * y.z, d2 * x.w * y.w);
        }
        if (kr == wave) {
            float* outp = grad_b + (size_t)r * RANK + lane * 4;
            nt_store4(outp, d2 * x.x * z.x, d2 * x.y * z.y,
                            d2 * x.z * z.z, d2 * x.w * z.w);
        }
    }
}

__global__ void zero_untouched_kernel(const int* __restrict__ wA,
                                      const int* __restrict__ wB,
                                      float* __restrict__ grad_a,
                                      float* __restrict__ grad_b) {
    int tid  = blockIdx.x * blockDim.x + threadIdx.x;
    int lane = threadIdx.x & 63;
    bool need = false;
    if (tid < N_ENT) {
        need = (wA[tid] < 0);
    } else if (tid < N_ENT + N_REL) {
        need = (wB[tid - N_ENT] < 0);
    }
    unsigned long long mask = __ballot(need);
    while (mask) {
        int src = __ffsll((long long)mask) - 1;
        mask &= mask - 1;
        int rowsel = __shfl(tid, src, 64);
        float* outp = (rowsel < N_ENT)
            ? (grad_a + (size_t)rowsel * RANK)
            : (grad_b + (size_t)(rowsel - N_ENT) * RANK);
        if (lane < RANK / 4)
            nt_store4(outp + lane * 4, 0.f, 0.f, 0.f, 0.f);
    }
}

extern "C" void kernel_launch(void* const* d_in, const int* in_sizes, int n_in,
                              void* d_out, int out_size, void* d_ws, size_t ws_size,
                              hipStream_t stream) {
    const int*   coo  = (const int*)d_in[0];    // (NNZ, 3) int32
    const float* vals = (const float*)d_in[1];  // (NNZ,)   fp32
    const float* a    = (const float*)d_in[2];  // (N_ENT, RANK)
    const float* b    = (const float*)d_in[3];  // (N_REL, RANK)

    float* loss   = (float*)d_out;                       // NNZ
    float* grad_a = loss + NNZ;                          // N_ENT*RANK
    float* grad_b = grad_a + (size_t)N_ENT * RANK;       // N_REL*RANK

    int* wA         = (int*)d_ws;                        // N_ENT ints
    int* wB         = wA + N_ENT;                        // WB_PAD ints
    int* partial_wB = wB + WB_PAD;                       // NB_COOP*WB_PAD ints

    // --- primary: single cooperative dispatch (phases P0..P4) ---
    void* args[] = {(void*)&coo, (void*)&vals, (void*)&a, (void*)&b,
                    (void*)&loss, (void*)&grad_a, (void*)&grad_b,
                    (void*)&wA, (void*)&wB, (void*)&partial_wB};
    hipError_t err = hipLaunchCooperativeKernel(
        (const void*)mega_kernel, dim3(NB_COOP), dim3(256), args, 0, stream);

    if (err != hipSuccess) {
        // --- fallback: round-5 multi-kernel path ---
        (void)hipMemsetAsync(wA, 0xFF, (size_t)N_ENT * sizeof(int), stream);
        winner_kernel<<<NB_WIN, 256, 0, stream>>>(coo, wA, partial_wB);
        wb_reduce_kernel<<<1, WB_PAD, 0, stream>>>(partial_wB, wB);
        {
            long long total = (long long)NNZ * 64;
            int threads = 256;
            long long blocks = (total + threads - 1) / threads;
            fused_kernel<<<(int)blocks, threads, 0, stream>>>(
                coo, vals, a, b, wA, wB, loss, grad_a, grad_b);
        }
        {
            int total   = N_ENT + N_REL;
            int threads = 256;
            int blocks  = (total + threads - 1) / threads;
            zero_untouched_kernel<<<blocks, threads, 0, stream>>>(
                wA, wB, grad_a, grad_b);
        }
    }
}

// Round 7
// 450.329 us; speedup vs baseline: 2.0960x; 2.0960x over previous
//
#include <hip/hip_runtime.h>
#include <hip/hip_bf16.h>

#define RANK   200
#define N_ENT  200000
#define N_REL  500
#define NNZ    500000
#define WB_STRIDE 16        // one wB slot per 64B cacheline (atomic spread)

// Native 4-float vector: __builtin_nontemporal_store requires a native
// vector type, not HIP's float4 class.
typedef float f32x4 __attribute__((ext_vector_type(4)));

__device__ __forceinline__ void nt_store4(float* p,
                                          float a, float b_, float c, float d) {
    f32x4 v = {a, b_, c, d};
    __builtin_nontemporal_store(v, (f32x4*)p);
}

// ---------------------------------------------------------------------------
// Winner semantics (numpy scatter-SET, last write wins):
//   grad_a[subj] = g_a (pass 1) then grad_a[obj] = g_c (pass 2 overwrites).
// wA key: subj write at nnz i -> i ; obj write -> NNZ+i.
// wB winner = max nnz index per relation.
// wB is spread one int per 64B line: 500k atomicMax over 500 DISTINCT lines
// (~1000 ops/line) instead of 32 packed lines (~15.6k ops/line, the
// serialization that cost ~189us in the original session). This deletes the
// LDS aggregation, the partial_wB buffer, and the wb_reduce dispatch.
// ---------------------------------------------------------------------------
__global__ void winner_kernel(const int* __restrict__ coo,
                              int* __restrict__ wA,
                              int* __restrict__ wB_spread) {
    int i = blockIdx.x * blockDim.x + threadIdx.x;
    if (i >= NNZ) return;
    int s = coo[3 * i + 0];
    int r = coo[3 * i + 1];
    int o = coo[3 * i + 2];
    atomicMax(&wA[s], i);                       // ~5 contenders per address
    atomicMax(&wA[o], NNZ + i);
    atomicMax(&wB_spread[r * WB_STRIDE], i);    // 1 line per relation
}

// ---------------------------------------------------------------------------
// Fused loss+grad+zero: one 64-lane wave per nnz. Lanes 0-49 load one float4
// from each of the 3 rows (800 B/row). Butterfly shfl_xor reduce leaves the
// dot product in EVERY lane, so gradient operands (x=a0, y=b1, z=a2) and d
// stay live in registers; winner-keyed rows are written directly.
// Wave i ALSO owns output row i (i < N_ENT+N_REL <= NNZ): if that row was
// never touched (winner key < 0) it writes zeros — disjoint from winner rows,
// so no race, and the separate zero kernel is gone.
// Output stores are non-temporal (write-once data; ~13us measured win).
// ---------------------------------------------------------------------------
__global__ void fused_kernel(const int* __restrict__ coo,
                             const float* __restrict__ vals,
                             const float* __restrict__ a,
                             const float* __restrict__ b,
                             const int* __restrict__ wA,
                             const int* __restrict__ wB_spread,
                             float* __restrict__ loss,
                             float* __restrict__ grad_a,
                             float* __restrict__ grad_b) {
    int wave = (blockIdx.x * blockDim.x + threadIdx.x) >> 6;
    int lane = threadIdx.x & 63;
    if (wave >= NNZ) return;
    int s = coo[3 * wave + 0];
    int r = coo[3 * wave + 1];
    int o = coo[3 * wave + 2];
    // winner lookups issued early (broadcast loads, overlap the row gathers)
    int ks = wA[s];
    int ko = wA[o];
    int kr = wB_spread[r * WB_STRIDE];

    float4 x = make_float4(0.f, 0.f, 0.f, 0.f);
    float4 y = x, z = x;
    float sum = 0.0f;
    if (lane < RANK / 4) {
        x = ((const float4*)(a + (size_t)s * RANK))[lane];
        y = ((const float4*)(b + (size_t)r * RANK))[lane];
        z = ((const float4*)(a + (size_t)o * RANK))[lane];
        sum = x.x * y.x * z.x + x.y * y.y * z.y
            + x.z * y.z * z.z + x.w * y.w * z.w;
    }
    #pragma unroll
    for (int off = 32; off > 0; off >>= 1)
        sum += __shfl_xor(sum, off, 64);        // every lane gets the total

    float d = sum - vals[wave];
    if (lane == 0) __builtin_nontemporal_store(d * d, &loss[wave]);
    float d2 = 2.0f * d;

    if (lane < RANK / 4) {
        if (ks == wave) {                       // g_a = d2 * b1 * a2
            float* outp = grad_a + (size_t)s * RANK + lane * 4;
            nt_store4(outp, d2 * y.x * z.x, d2 * y.y * z.y,
                            d2 * y.z * z.z, d2 * y.w * z.w);
        }
        if (ko == NNZ + wave) {                 // g_c = d2 * a0 * b1
            float* outp = grad_a + (size_t)o * RANK + lane * 4;
            nt_store4(outp, d2 * x.x * y.x, d2 * x.y * y.y,
                            d2 * x.z * y.z, d2 * x.w * y.w);
        }
        if (kr == wave) {                       // g_b = d2 * a0 * a2
            float* outp = grad_b + (size_t)r * RANK + lane * 4;
            nt_store4(outp, d2 * x.x * z.x, d2 * x.y * z.y,
                            d2 * x.z * z.z, d2 * x.w * z.w);
        }
    }

    // ---- zero-fill: wave i owns output row i ----
    if (wave < N_ENT + N_REL) {
        bool is_ent = wave < N_ENT;
        int key = is_ent ? wA[wave] : wB_spread[(wave - N_ENT) * WB_STRIDE];
        if (key < 0) {
            float* outp = is_ent
                ? (grad_a + (size_t)wave * RANK)
                : (grad_b + (size_t)(wave - N_ENT) * RANK);
            if (lane < RANK / 4)
                nt_store4(outp + lane * 4, 0.f, 0.f, 0.f, 0.f);
        }
    }
}

extern "C" void kernel_launch(void* const* d_in, const int* in_sizes, int n_in,
                              void* d_out, int out_size, void* d_ws, size_t ws_size,
                              hipStream_t stream) {
    const int*   coo  = (const int*)d_in[0];    // (NNZ, 3) int32
    const float* vals = (const float*)d_in[1];  // (NNZ,)   fp32
    const float* a    = (const float*)d_in[2];  // (N_ENT, RANK)
    const float* b    = (const float*)d_in[3];  // (N_REL, RANK)

    float* loss   = (float*)d_out;                       // NNZ
    float* grad_a = loss + NNZ;                          // N_ENT*RANK
    float* grad_b = grad_a + (size_t)N_ENT * RANK;       // N_REL*RANK

    int* wA        = (int*)d_ws;                         // N_ENT ints
    int* wB_spread = wA + N_ENT;                         // N_REL*WB_STRIDE ints

    // one memset covers wA + wB_spread (adjacent): 0xFF bytes -> -1
    (void)hipMemsetAsync(wA, 0xFF,
                         (size_t)(N_ENT + N_REL * WB_STRIDE) * sizeof(int),
                         stream);

    {
        int threads = 256;
        int blocks  = (NNZ + threads - 1) / threads;
        winner_kernel<<<blocks, threads, 0, stream>>>(coo, wA, wB_spread);
    }
    {
        long long total = (long long)NNZ * 64;
        int threads = 256;
        long long blocks = (total + threads - 1) / threads;
        fused_kernel<<<(int)blocks, threads, 0, stream>>>(coo, vals, a, b,
                                                          wA, wB_spread,
                                                          loss, grad_a, grad_b);
    }
}

// Round 8
// 437.966 us; speedup vs baseline: 2.1552x; 1.0282x over previous
//
#include <hip/hip_runtime.h>
#include <hip/hip_bf16.h>

#define RANK   200
#define N_ENT  200000
#define N_REL  500
#define NNZ    500000
#define WB_STRIDE 16        // one wB slot per 64B cacheline (atomic spread)

// Native 4-float vector: __builtin_nontemporal_store requires a native
// vector type, not HIP's float4 class.
typedef float f32x4 __attribute__((ext_vector_type(4)));

__device__ __forceinline__ void nt_store4(float* p,
                                          float a, float b_, float c, float d) {
    f32x4 v = {a, b_, c, d};
    __builtin_nontemporal_store(v, (f32x4*)p);
}

// ---------------------------------------------------------------------------
// Winner semantics (numpy scatter-SET, last write wins):
//   grad_a[subj] = g_a (pass 1) then grad_a[obj] = g_c (pass 2 overwrites).
// wA key: subj write at nnz i -> i ; obj write -> NNZ+i.
// wB winner = max nnz index per relation, one slot per 64B line (500 distinct
// lines, ~1000 ops/line — line contention, not address count, was the
// original 189us serialization).
// ---------------------------------------------------------------------------
__global__ void winner_kernel(const int* __restrict__ coo,
                              int* __restrict__ wA,
                              int* __restrict__ wB_spread) {
    int i = blockIdx.x * blockDim.x + threadIdx.x;
    if (i >= NNZ) return;
    int s = coo[3 * i + 0];
    int r = coo[3 * i + 1];
    int o = coo[3 * i + 2];
    atomicMax(&wA[s], i);                       // ~5 contenders per address
    atomicMax(&wA[o], NNZ + i);
    atomicMax(&wB_spread[r * WB_STRIDE], i);    // 1 line per relation
}

// ---------------------------------------------------------------------------
// Fused loss+grad+zero, TWO nnz per wave for memory-level parallelism.
// Rate analysis (r0 vs r7): loss-only ran at 2.63 TB/s, fused at 3.27 TB/s —
// +193 MB of write traffic cost only +25us, so the pass has latency slack.
// Per-wave MLP was 3 row-loads then a dead shuffle+store epilogue; issuing 6
// row-loads for two nnz up front and interleaving the two reduces overlaps
// one nnz's latency under the other's compute.
// Wave i also owns output rows 2i,2i+1 for untouched-row zero-fill (disjoint
// from winner-written rows; no race). Output stores non-temporal (small
// measured win; write-once data).
// ---------------------------------------------------------------------------
__global__ void fused_kernel(const int* __restrict__ coo,
                             const float* __restrict__ vals,
                             const float* __restrict__ a,
                             const float* __restrict__ b,
                             const int* __restrict__ wA,
                             const int* __restrict__ wB_spread,
                             float* __restrict__ loss,
                             float* __restrict__ grad_a,
                             float* __restrict__ grad_b) {
    int w    = (blockIdx.x * blockDim.x + threadIdx.x) >> 6;
    int lane = threadIdx.x & 63;
    int i0 = 2 * w;
    int i1 = 2 * w + 1;                 // NNZ even: i1 < NNZ iff i0 < NNZ
    if (i0 >= NNZ) return;

    // coo for both nnz (adjacent lines), then winner keys (broadcast loads)
    int s0 = coo[3 * i0 + 0], r0 = coo[3 * i0 + 1], o0 = coo[3 * i0 + 2];
    int s1 = coo[3 * i1 + 0], r1 = coo[3 * i1 + 1], o1 = coo[3 * i1 + 2];
    int ks0 = wA[s0], ko0 = wA[o0], kr0 = wB_spread[r0 * WB_STRIDE];
    int ks1 = wA[s1], ko1 = wA[o1], kr1 = wB_spread[r1 * WB_STRIDE];

    float4 x0 = make_float4(0.f, 0.f, 0.f, 0.f);
    float4 y0 = x0, z0 = x0, x1 = x0, y1 = x0, z1 = x0;
    float sum0 = 0.0f, sum1 = 0.0f;
    if (lane < RANK / 4) {
        // issue all 6 row-loads before any use
        x0 = ((const float4*)(a + (size_t)s0 * RANK))[lane];
        y0 = ((const float4*)(b + (size_t)r0 * RANK))[lane];
        z0 = ((const float4*)(a + (size_t)o0 * RANK))[lane];
        x1 = ((const float4*)(a + (size_t)s1 * RANK))[lane];
        y1 = ((const float4*)(b + (size_t)r1 * RANK))[lane];
        z1 = ((const float4*)(a + (size_t)o1 * RANK))[lane];
        sum0 = x0.x * y0.x * z0.x + x0.y * y0.y * z0.y
             + x0.z * y0.z * z0.z + x0.w * y0.w * z0.w;
        sum1 = x1.x * y1.x * z1.x + x1.y * y1.y * z1.y
             + x1.z * y1.z * z1.z + x1.w * y1.w * z1.w;
    }
    #pragma unroll
    for (int off = 32; off > 0; off >>= 1) {    // interleaved: chains overlap
        sum0 += __shfl_xor(sum0, off, 64);
        sum1 += __shfl_xor(sum1, off, 64);
    }

    float d0 = sum0 - vals[i0];
    float d1 = sum1 - vals[i1];
    if (lane == 0) {
        __builtin_nontemporal_store(d0 * d0, &loss[i0]);
        __builtin_nontemporal_store(d1 * d1, &loss[i1]);
    }
    float e0 = 2.0f * d0;
    float e1 = 2.0f * d1;

    if (lane < RANK / 4) {
        if (ks0 == i0) {                        // g_a = e * b1 * a2
            float* outp = grad_a + (size_t)s0 * RANK + lane * 4;
            nt_store4(outp, e0 * y0.x * z0.x, e0 * y0.y * z0.y,
                            e0 * y0.z * z0.z, e0 * y0.w * z0.w);
        }
        if (ko0 == NNZ + i0) {                  // g_c = e * a0 * b1
            float* outp = grad_a + (size_t)o0 * RANK + lane * 4;
            nt_store4(outp, e0 * x0.x * y0.x, e0 * x0.y * y0.y,
                            e0 * x0.z * y0.z, e0 * x0.w * y0.w);
        }
        if (kr0 == i0) {                        // g_b = e * a0 * a2
            float* outp = grad_b + (size_t)r0 * RANK + lane * 4;
            nt_store4(outp, e0 * x0.x * z0.x, e0 * x0.y * z0.y,
                            e0 * x0.z * z0.z, e0 * x0.w * z0.w);
        }
        if (ks1 == i1) {
            float* outp = grad_a + (size_t)s1 * RANK + lane * 4;
            nt_store4(outp, e1 * y1.x * z1.x, e1 * y1.y * z1.y,
                            e1 * y1.z * z1.z, e1 * y1.w * z1.w);
        }
        if (ko1 == NNZ + i1) {
            float* outp = grad_a + (size_t)o1 * RANK + lane * 4;
            nt_store4(outp, e1 * x1.x * y1.x, e1 * x1.y * y1.y,
                            e1 * x1.z * y1.z, e1 * x1.w * y1.w);
        }
        if (kr1 == i1) {
            float* outp = grad_b + (size_t)r1 * RANK + lane * 4;
            nt_store4(outp, e1 * x1.x * z1.x, e1 * x1.y * z1.y,
                            e1 * x1.z * z1.z, e1 * x1.w * z1.w);
        }
    }

    // ---- zero-fill: wave owns output rows i0 and i1 ----
    #pragma unroll
    for (int t = 0; t < 2; ++t) {
        int row = i0 + t;
        if (row < N_ENT + N_REL) {
            bool is_ent = row < N_ENT;
            int key = is_ent ? wA[row]
                             : wB_spread[(row - N_ENT) * WB_STRIDE];
            if (key < 0) {
                float* outp = is_ent
                    ? (grad_a + (size_t)row * RANK)
                    : (grad_b + (size_t)(row - N_ENT) * RANK);
                if (lane < RANK / 4)
                    nt_store4(outp + lane * 4, 0.f, 0.f, 0.f, 0.f);
            }
        }
    }
}

extern "C" void kernel_launch(void* const* d_in, const int* in_sizes, int n_in,
                              void* d_out, int out_size, void* d_ws, size_t ws_size,
                              hipStream_t stream) {
    const int*   coo  = (const int*)d_in[0];    // (NNZ, 3) int32
    const float* vals = (const float*)d_in[1];  // (NNZ,)   fp32
    const float* a    = (const float*)d_in[2];  // (N_ENT, RANK)
    const float* b    = (const float*)d_in[3];  // (N_REL, RANK)

    float* loss   = (float*)d_out;                       // NNZ
    float* grad_a = loss + NNZ;                          // N_ENT*RANK
    float* grad_b = grad_a + (size_t)N_ENT * RANK;       // N_REL*RANK

    int* wA        = (int*)d_ws;                         // N_ENT ints
    int* wB_spread = wA + N_ENT;                         // N_REL*WB_STRIDE ints

    // one memset covers wA + wB_spread (adjacent): 0xFF bytes -> -1
    (void)hipMemsetAsync(wA, 0xFF,
                         (size_t)(N_ENT + N_REL * WB_STRIDE) * sizeof(int),
                         stream);

    {
        int threads = 256;
        int blocks  = (NNZ + threads - 1) / threads;
        winner_kernel<<<blocks, threads, 0, stream>>>(coo, wA, wB_spread);
    }
    {
        long long waves  = NNZ / 2;                      // 2 nnz per wave
        long long total  = waves * 64;
        int threads = 256;
        long long blocks = (total + threads - 1) / threads;
        fused_kernel<<<(int)blocks, threads, 0, stream>>>(coo, vals, a, b,
                                                          wA, wB_spread,
                                                          loss, grad_a, grad_b);
    }
}